// Round 8
// baseline (141.084 us; speedup 1.0000x reference)
//
#include <hip/hip_runtime.h>

#define FEAT   128
#define RS     64            // nodes per range
#define RSH    6             // log2(RS)
#define CAPN   64            // bucket slots per node (global deg max ~45 at Poisson(16))
#define NRMAX  1024          // max ranges (n <= 65536)
#define PB     64            // partition blocks (= stripes per range)
#define SLOTS  64            // slots per (range, block) stripe; lambda=16, P(>64)~1e-19
#define STR    (PB * SLOTS)  // 4096 slots per range
#define HBPB   128           // rows per hb-pack block

typedef short bf16x8 __attribute__((ext_vector_type(8)));
typedef float f32x4  __attribute__((ext_vector_type(4)));

__device__ __forceinline__ unsigned pack_bf16x2(float x, float y) {
    unsigned ux = __float_as_uint(x);
    ux = (ux + 0x7fffu + ((ux >> 16) & 1u)) >> 16;          // RNE, low half
    unsigned uy = __float_as_uint(y);
    uy = (uy + 0x7fffu + ((uy >> 16) & 1u)) & 0xffff0000u;  // RNE, high half
    return uy | ux;
}

__device__ __forceinline__ bf16x8 pack8(float4 a, float4 b) {
    uint4 u = make_uint4(pack_bf16x2(a.x, a.y), pack_bf16x2(a.z, a.w),
                         pack_bf16x2(b.x, b.y), pack_bf16x2(b.z, b.w));
    return __builtin_bit_cast(bf16x8, u);
}

__device__ __forceinline__ f32x4 unpack2(unsigned x, unsigned y) {
    return (f32x4){__uint_as_float(x << 16), __uint_as_float(x & 0xffff0000u),
                   __uint_as_float(y << 16), __uint_as_float(y & 0xffff0000u)};
}

// ---------------- K1: prep = [single-pass static-stripe partition] ++ [hb-pack] ----------------
// R7 verified: static (range,block) stripes, zero global atomics, one pass; prep ~12us
// (was ~35 with the two-scan reserve partition). UNCHANGED in R8.
__global__ __launch_bounds__(512) void prep_kernel(
    const float* __restrict__ h, const int* __restrict__ src,
    const int* __restrict__ dst, uint4* __restrict__ hb4,
    unsigned* __restrict__ seg, int* __restrict__ cnt,
    int n, int E, int NR, int part_blocks)
{
    __shared__ int hist[NRMAX];

    const int bid = blockIdx.x;
    const int tid = threadIdx.x;

    if (bid < part_blocks) {
        const int epb = (((E + PB - 1) / PB) + 3) & ~3;   // 4-aligned edges per block
        const int e0  = bid * epb;
        int e1 = e0 + epb; if (e1 > E) e1 = E;

        for (int i = tid; i < NR; i += 512) hist[i] = 0;
        __syncthreads();

        if (e0 < e1) {
            const int nq4 = (e1 - e0) >> 2;
            const int4* __restrict__ d4p = (const int4*)(dst + e0);
            const int4* __restrict__ s4p = (const int4*)(src + e0);
            const size_t sb = (size_t)bid * SLOTS;

            for (int i = tid; i < nq4; i += 512) {
                int4 d = d4p[i];
                int4 s = s4p[i];
#pragma unroll
                for (int u = 0; u < 4; ++u) {
                    int dv = (u == 0) ? d.x : (u == 1) ? d.y : (u == 2) ? d.z : d.w;
                    int sv = (u == 0) ? s.x : (u == 1) ? s.y : (u == 2) ? s.z : s.w;
                    int rid  = dv >> RSH;
                    int slot = atomicAdd(&hist[rid], 1);
                    if (slot < SLOTS)
                        seg[(size_t)rid * STR + sb + slot] =
                            (unsigned)(((dv & (RS - 1)) << 16) | (sv & 0xffff));
                }
            }
            for (int e = e0 + (nq4 << 2) + tid; e < e1; e += 512) {
                int dv = dst[e], sv = src[e];
                int rid  = dv >> RSH;
                int slot = atomicAdd(&hist[rid], 1);
                if (slot < SLOTS)
                    seg[(size_t)rid * STR + sb + slot] =
                        (unsigned)(((dv & (RS - 1)) << 16) | (sv & 0xffff));
            }
        }
        __syncthreads();

        for (int r = tid; r < NR; r += 512) {
            int c = hist[r]; if (c > SLOTS) c = SLOTS;
            cnt[(size_t)r * PB + bid] = c;
        }
        return;
    }

    // ---- hb-pack: quarter-wave (16 lanes) packs one 256-B bf16 row ----
    const int r0  = (bid - part_blocks) * HBPB;
    const int qid = tid >> 4;
    const int ql  = tid & 15;
    const float4* __restrict__ h4 = (const float4*)h;
    int rend = r0 + HBPB; if (rend > n) rend = n;
    for (int r = r0 + qid; r < rend; r += 32) {
        float4 a0 = h4[(size_t)r * 32 + ql * 2];
        float4 a1 = h4[(size_t)r * 32 + ql * 2 + 1];
        hb4[(size_t)r * 16 + ql] = __builtin_bit_cast(uint4, pack8(a0, a1));
    }
}

// ---------------- K2: [bin+gather per range] ++ [gemm -> out] in ONE grid ----------------
// R7 post-mortem: the issue/consume node pipeline was DESTROYED by the compiler (VGPR=56,
// not the ~128 the two buffer sets need): inlined matching-predicate loads were sunk to
// their uses -> MLP unchanged, overhead added, 48->75us. R8: pair-node interleave -- one
// loop iteration issues 4 predicated row-loads for node A AND 4 for node B (8 independent
// loads in ONE basic block, all consumed before the back-edge -> compiler's natural
// schedule clusters them: real MLP 8). dmax=max(degA,degB) wave-uniform; per-edge
// predication replaces the tail; lbkt idx t+12+q <= 63 needs no clamp.
// INVARIANT: shfl_down reduce under FULL exec (pair-loop break wave-uniform); only hb
// load+accumulate predicated. Gemm blocks after gather blocks (R6-verified overlap).
__global__ __launch_bounds__(512) void gather_gemm_kernel(
    const float* __restrict__ h, const float* __restrict__ W,
    const float* __restrict__ b, const uint4* __restrict__ hb4,
    const unsigned* __restrict__ seg, const int* __restrict__ cnt,
    float* __restrict__ out, float* __restrict__ agg, int n, int NR)
{
    __shared__ int            lcnt[RS];
    __shared__ int            scnt[PB];
    __shared__ unsigned short lbkt[RS * CAPN];   // 8 KB; slots >= count stay garbage (never read)

    const int bid = blockIdx.x;
    const int tid = threadIdx.x;

    if (bid < NR) {
        const int base = bid * RS;
        int rsv = n - base; if (rsv > RS) rsv = RS;

        if (tid < RS) lcnt[tid] = 0;
        if (tid < PB) scnt[tid] = cnt[(size_t)bid * PB + tid];
        __syncthreads();

        // bin: scan own 4096-slot row, gated by per-stripe counts (R7, verified)
        const int4* __restrict__ seg4 = (const int4*)seg + (size_t)bid * (STR / 4);
#pragma unroll
        for (int wv = 0; wv < STR / 4 / 512; ++wv) {    // 2 iterations
            int j4 = wv * 512 + tid;
            int4 pv = seg4[j4];
            int s0 = j4 << 2;
#pragma unroll
            for (int u = 0; u < 4; ++u) {
                int sl = s0 + u;
                unsigned p = (u == 0) ? (unsigned)pv.x : (u == 1) ? (unsigned)pv.y
                           : (u == 2) ? (unsigned)pv.z : (unsigned)pv.w;
                if ((sl & (SLOTS - 1)) < scnt[sl >> 6]) {
                    int nd = (int)(p >> 16);
                    int k  = atomicAdd(&lcnt[nd], 1);
                    if (k < CAPN) lbkt[(nd << 6) + k] = (unsigned short)(p & 0xffffu);
                }
            }
        }
        __syncthreads();

        const int lane = tid & 63;
        const int w    = tid >> 6;
        const int q    = lane >> 4, ql = lane & 15;
        const int nb   = w << 3;          // this wave's first node

        for (int k = 0; k < 8; k += 2) {
            const int ndA = nb + k, ndB = nb + k + 1;
            if (ndA >= rsv) break;                      // wave-uniform
            const bool hasB = (ndB < rsv);              // wave-uniform
            int degA = lcnt[ndA]; degA = degA > CAPN ? CAPN : degA;
            int degB = hasB ? lcnt[ndB] : 0; degB = degB > CAPN ? CAPN : degB;
            const int dmax = degA > degB ? degA : degB; // wave-uniform (LDS broadcast)
            const int rbA = ndA << 6, rbB = ndB << 6;   // ndB <= 63 always: lbkt read safe

            f32x4 alA0 = {0.f,0.f,0.f,0.f}, ahA0 = {0.f,0.f,0.f,0.f};
            f32x4 alA1 = {0.f,0.f,0.f,0.f}, ahA1 = {0.f,0.f,0.f,0.f};
            f32x4 alB0 = {0.f,0.f,0.f,0.f}, ahB0 = {0.f,0.f,0.f,0.f};
            f32x4 alB1 = {0.f,0.f,0.f,0.f}, ahB1 = {0.f,0.f,0.f,0.f};

            for (int t = 0; t < dmax; t += 16) {
                const int i0 = t + q, i1 = t + 4 + q, i2 = t + 8 + q, i3 = t + 12 + q;
                // 8 independent eid reads (LDS) ...
                int eA0 = lbkt[rbA + i0], eA1 = lbkt[rbA + i1];
                int eA2 = lbkt[rbA + i2], eA3 = lbkt[rbA + i3];
                int eB0 = lbkt[rbB + i0], eB1 = lbkt[rbB + i1];
                int eB2 = lbkt[rbB + i2], eB3 = lbkt[rbB + i3];
                // ... then 8 independent predicated row loads (MLP 8), consumed below
                uint4 vA0, vA1, vA2, vA3, vB0, vB1, vB2, vB3;
                if (i0 < degA) vA0 = hb4[(size_t)eA0 * 16 + ql];
                if (i1 < degA) vA1 = hb4[(size_t)eA1 * 16 + ql];
                if (i2 < degA) vA2 = hb4[(size_t)eA2 * 16 + ql];
                if (i3 < degA) vA3 = hb4[(size_t)eA3 * 16 + ql];
                if (i0 < degB) vB0 = hb4[(size_t)eB0 * 16 + ql];
                if (i1 < degB) vB1 = hb4[(size_t)eB1 * 16 + ql];
                if (i2 < degB) vB2 = hb4[(size_t)eB2 * 16 + ql];
                if (i3 < degB) vB3 = hb4[(size_t)eB3 * 16 + ql];
                if (i0 < degA) { alA0 += unpack2(vA0.x, vA0.y); ahA0 += unpack2(vA0.z, vA0.w); }
                if (i1 < degA) { alA1 += unpack2(vA1.x, vA1.y); ahA1 += unpack2(vA1.z, vA1.w); }
                if (i2 < degA) { alA0 += unpack2(vA2.x, vA2.y); ahA0 += unpack2(vA2.z, vA2.w); }
                if (i3 < degA) { alA1 += unpack2(vA3.x, vA3.y); ahA1 += unpack2(vA3.z, vA3.w); }
                if (i0 < degB) { alB0 += unpack2(vB0.x, vB0.y); ahB0 += unpack2(vB0.z, vB0.w); }
                if (i1 < degB) { alB1 += unpack2(vB1.x, vB1.y); ahB1 += unpack2(vB1.z, vB1.w); }
                if (i2 < degB) { alB0 += unpack2(vB2.x, vB2.y); ahB0 += unpack2(vB2.z, vB2.w); }
                if (i3 < degB) { alB1 += unpack2(vB3.x, vB3.y); ahB1 += unpack2(vB3.z, vB3.w); }
            }

            alA0 += alA1; ahA0 += ahA1;
            alB0 += alB1; ahB0 += ahB1;

#pragma unroll
            for (int j = 0; j < 4; ++j) {               // FULL exec mask
                alA0[j] += __shfl_down(alA0[j], 32);
                ahA0[j] += __shfl_down(ahA0[j], 32);
                alB0[j] += __shfl_down(alB0[j], 32);
                ahB0[j] += __shfl_down(ahB0[j], 32);
                alA0[j] += __shfl_down(alA0[j], 16);
                ahA0[j] += __shfl_down(ahA0[j], 16);
                alB0[j] += __shfl_down(alB0[j], 16);
                ahB0[j] += __shfl_down(ahB0[j], 16);
            }

            if (q == 0) {
                f32x4* aggv = (f32x4*)agg;
                __builtin_nontemporal_store(alA0, &aggv[(size_t)(base + ndA) * 32 + ql * 2]);
                __builtin_nontemporal_store(ahA0, &aggv[(size_t)(base + ndA) * 32 + ql * 2 + 1]);
                if (hasB) {
                    __builtin_nontemporal_store(alB0, &aggv[(size_t)(base + ndB) * 32 + ql * 2]);
                    __builtin_nontemporal_store(ahB0, &aggv[(size_t)(base + ndB) * 32 + ql * 2 + 1]);
                }
            }
        }
        return;
    }

    // ---- gemm path: wave = rows [r0g, r0g+32) x cols [ch*64, ch*64+64) ----
    const int gbid = bid - NR;
    const int w    = tid >> 6;
    const int lane = tid & 63;
    const int m    = lane & 15, quad = lane >> 4;
    const int r0g  = gbid * 128 + (w >> 1) * 32;
    const int ch   = w & 1;
    if (r0g >= n) return;

    const float4* __restrict__ h4 = (const float4*)h;   // row stride 32 float4
    const float4* __restrict__ W4 = (const float4*)W;

    bf16x8 af[2][4];
#pragma unroll
    for (int mt = 0; mt < 2; ++mt) {
        int gr = r0g + mt * 16 + m;
#pragma unroll
        for (int ks = 0; ks < 4; ++ks) {
            float4 a0 = h4[(size_t)gr * 32 + ks * 8 + quad * 2];
            float4 a1 = h4[(size_t)gr * 32 + ks * 8 + quad * 2 + 1];
            af[mt][ks] = pack8(a0, a1);
        }
    }

    f32x4 acc[2][4];
#pragma unroll
    for (int mt = 0; mt < 2; ++mt)
#pragma unroll
        for (int nn = 0; nn < 4; ++nn) acc[mt][nn] = (f32x4){0.f, 0.f, 0.f, 0.f};

#pragma unroll
    for (int nn = 0; nn < 4; ++nn) {
        int c = (ch * 4 + nn) * 16 + m;
#pragma unroll
        for (int ks = 0; ks < 4; ++ks) {
            float4 b0 = W4[(size_t)c * 32 + ks * 8 + quad * 2];
            float4 b1 = W4[(size_t)c * 32 + ks * 8 + quad * 2 + 1];
            bf16x8 bf = pack8(b0, b1);
#pragma unroll
            for (int mt = 0; mt < 2; ++mt)
                acc[mt][nn] = __builtin_amdgcn_mfma_f32_16x16x32_bf16(
                    af[mt][ks], bf, acc[mt][nn], 0, 0, 0);
        }
    }

#pragma unroll
    for (int nn = 0; nn < 4; ++nn) {
        int col = (ch * 4 + nn) * 16 + m;
        float bias = b[col];
#pragma unroll
        for (int mt = 0; mt < 2; ++mt)
#pragma unroll
            for (int r = 0; r < 4; ++r) {
                int gr = r0g + mt * 16 + quad * 4 + r;
                if (gr < n)
                    __builtin_nontemporal_store(acc[mt][nn][r] + bias,
                                                &out[(size_t)gr * FEAT + col]);
            }
    }
}

// ---------------- fallback path (ws too small / odd shapes): f32 GEMM + atomic scatter ----------------
__global__ __launch_bounds__(256, 2) void gemm_f32_kernel(
    const float* __restrict__ h, const float* __restrict__ W,
    const float* __restrict__ b, float* __restrict__ out, int nrows)
{
    __shared__ float4 wsh[128 * 8];
    __shared__ float4 hsh[64 * 8];
    const int tid = threadIdx.x;
    const int tx  = tid & 31;
    const int ty  = tid >> 5;
    const int r0  = blockIdx.x * 64;
    const float4* __restrict__ W4 = (const float4*)W;
    const float4* __restrict__ h4 = (const float4*)h;
    float acc[8][4];
#pragma unroll
    for (int i = 0; i < 8; ++i)
#pragma unroll
        for (int j = 0; j < 4; ++j) acc[i][j] = 0.f;
    for (int p = 0; p < 4; ++p) {
        if (p) __syncthreads();
#pragma unroll
        for (int l = 0; l < 4; ++l) {
            int flat = l * 256 + tid;
            int c = flat >> 3, kc = flat & 7;
            wsh[c * 8 + (kc ^ ((c >> 2) & 7))] = W4[c * 32 + p * 8 + kc];
        }
#pragma unroll
        for (int l = 0; l < 2; ++l) {
            int flat = l * 256 + tid;
            int r = flat >> 3, kc = flat & 7;
            int gr = r0 + r;
            float4 v = make_float4(0.f, 0.f, 0.f, 0.f);
            if (gr < nrows) v = h4[(size_t)gr * 32 + p * 8 + kc];
            hsh[r * 8 + (kc ^ ((r >> 2) & 7))] = v;
        }
        __syncthreads();
#pragma unroll
        for (int kc = 0; kc < 8; ++kc) {
            float4 wv[4], hv[8];
#pragma unroll
            for (int j = 0; j < 4; ++j) wv[j] = wsh[(4 * tx + j) * 8 + (kc ^ (tx & 7))];
#pragma unroll
            for (int i = 0; i < 8; ++i) {
                int r = 8 * ty + i;
                hv[i] = hsh[r * 8 + (kc ^ ((r >> 2) & 7))];
            }
#pragma unroll
            for (int i = 0; i < 8; ++i)
#pragma unroll
                for (int j = 0; j < 4; ++j) {
                    acc[i][j] += hv[i].x * wv[j].x;
                    acc[i][j] += hv[i].y * wv[j].y;
                    acc[i][j] += hv[i].z * wv[j].z;
                    acc[i][j] += hv[i].w * wv[j].w;
                }
        }
    }
    const float4 bj = ((const float4*)b)[tx];
    float4* out4 = (float4*)out;
#pragma unroll
    for (int i = 0; i < 8; ++i) {
        int gr = r0 + 8 * ty + i;
        if (gr < nrows) {
            float4 o;
            o.x = acc[i][0] + bj.x; o.y = acc[i][1] + bj.y;
            o.z = acc[i][2] + bj.z; o.w = acc[i][3] + bj.w;
            out4[(size_t)gr * 32 + tx] = o;
        }
    }
}

__global__ __launch_bounds__(256) void scatter_add_kernel(
    const float* __restrict__ h, const int* __restrict__ src,
    const int* __restrict__ dst, float* __restrict__ agg, int E)
{
    int gid  = blockIdx.x * 256 + threadIdx.x;
    int e    = gid >> 6;
    int lane = gid & 63;
    if (e >= E) return;
    int s = src[e];
    int d = dst[e];
    const float2* hp = (const float2*)(h + (size_t)s * FEAT);
    float2 v = hp[lane];
    float* ap = agg + (size_t)d * FEAT + 2 * lane;
    unsafeAtomicAdd(ap,     v.x);
    unsafeAtomicAdd(ap + 1, v.y);
}

extern "C" void kernel_launch(void* const* d_in, const int* in_sizes, int n_in,
                              void* d_out, int out_size, void* d_ws, size_t ws_size,
                              hipStream_t stream) {
    const float* h   = (const float*)d_in[0];
    const float* W   = (const float*)d_in[1];
    const float* b   = (const float*)d_in[2];
    const int*   src = (const int*)d_in[3];
    const int*   dst = (const int*)d_in[4];

    const int n = in_sizes[0] / FEAT;   // 40000 nodes
    const int E = in_sizes[3];          // 640000 edges

    float* out = (float*)d_out;
    float* agg = out + (size_t)n * FEAT;

    const int NR = (n + RS - 1) >> RSH;   // ranges of 64 nodes

    // ws layout: [hb: n*256 B][seg: NR*STR*4 B][cnt: NR*PB*4 B]
    size_t hb_bytes  = (size_t)n * FEAT * 2;
    size_t seg_bytes = (size_t)NR * STR * 4;
    size_t cnt_bytes = (size_t)NR * PB * 4;
    size_t need = hb_bytes + seg_bytes + cnt_bytes;

    bool fast = (ws_size >= need) && (n > 0) && (n <= 65536) && (NR <= NRMAX);

    if (fast) {
        uint4*    hb  = (uint4*)d_ws;
        unsigned* seg = (unsigned*)((char*)d_ws + hb_bytes);
        int*      cnt = (int*)((char*)d_ws + hb_bytes + seg_bytes);

        int hbp_blocks = (n + HBPB - 1) / HBPB;
        prep_kernel<<<dim3(PB + hbp_blocks), dim3(512), 0, stream>>>(
            h, src, dst, hb, seg, cnt, n, E, NR, PB);

        int gemm_blocks = (n + 127) / 128;        // 128 rows/block (8 waves)
        gather_gemm_kernel<<<dim3(NR + gemm_blocks), dim3(512), 0, stream>>>(
            h, W, b, hb, seg, cnt, out, agg, n, NR);
    } else {
        gemm_f32_kernel<<<dim3((n + 63) / 64), dim3(256), 0, stream>>>(h, W, b, out, n);
        (void)hipMemsetAsync(agg, 0, (size_t)n * FEAT * sizeof(float), stream);
        int nblocks = (int)(((long long)E * 64 + 255) / 256);
        scatter_add_kernel<<<dim3(nblocks), dim3(256), 0, stream>>>(h, src, dst, agg, E);
    }
}

// Round 9
// 140.779 us; speedup vs baseline: 1.0022x; 1.0022x over previous
//
#include <hip/hip_runtime.h>

#define FEAT   128
#define RS     64            // nodes per range
#define RSH    6             // log2(RS)
#define CAPN   64            // bucket slots per node (global deg max ~45 at Poisson(16))
#define NRMAX  1024          // max ranges (n <= 65536)
#define PB     512           // partition blocks (= stripes per range)
#define SLOTS  16            // slots per (range,block) stripe; lambda=2, P(>16)~5e-11
#define SLOTSH 4             // log2(SLOTS)
#define STR    (PB * SLOTS)  // 8192 slots per range

typedef short bf16x8 __attribute__((ext_vector_type(8)));
typedef float f32x4  __attribute__((ext_vector_type(4)));

__device__ __forceinline__ unsigned pack_bf16x2(float x, float y) {
    unsigned ux = __float_as_uint(x);
    ux = (ux + 0x7fffu + ((ux >> 16) & 1u)) >> 16;          // RNE, low half
    unsigned uy = __float_as_uint(y);
    uy = (uy + 0x7fffu + ((uy >> 16) & 1u)) & 0xffff0000u;  // RNE, high half
    return uy | ux;
}

__device__ __forceinline__ bf16x8 pack8(float4 a, float4 b) {
    uint4 u = make_uint4(pack_bf16x2(a.x, a.y), pack_bf16x2(a.z, a.w),
                         pack_bf16x2(b.x, b.y), pack_bf16x2(b.z, b.w));
    return __builtin_bit_cast(bf16x8, u);
}

__device__ __forceinline__ f32x4 unpack2(unsigned x, unsigned y) {
    return (f32x4){__uint_as_float(x << 16), __uint_as_float(x & 0xffff0000u),
                   __uint_as_float(y << 16), __uint_as_float(y & 0xffff0000u)};
}

// ---------------- K1: prep = [static-stripe partition + hb-pack], 512 uniform blocks ----------------
// R8 post-mortem: totals invariant (140+-1) to a 26us K2 swing -- serial accounting can't
// fit both R7 and R8, so either prep or launch overhead is larger than modeled. R9 probe:
// make prep PROVABLY tiny. Partition parallelism 64 -> 512 blocks (1250 edges/block, 2.4
// int4/thread) and hb-pack folded into the same uniform blocks. Stripe: (range, block)
// with SLOTS=16 (lambda=2, overflow P ~2e-5 -> dropped-edge risk negligible). Zero global
// atomics, one pass, no memsets. If total drops ~30us, prep was the hidden cost; if total
// stays ~140 with prep <=10 and K2 walled at 48, remaining time is harness floor.
__global__ __launch_bounds__(512) void prep_kernel(
    const float* __restrict__ h, const int* __restrict__ src,
    const int* __restrict__ dst, uint4* __restrict__ hb4,
    unsigned* __restrict__ seg, int* __restrict__ cnt,
    int n, int E, int NR)
{
    __shared__ int hist[NRMAX];

    const int bid = blockIdx.x;
    const int tid = threadIdx.x;

    for (int i = tid; i < NR; i += 512) hist[i] = 0;
    __syncthreads();

    const int epb = (((E + PB - 1) / PB) + 3) & ~3;   // 4-aligned edges per block
    const int e0  = bid * epb;
    int e1 = e0 + epb; if (e1 > E) e1 = E;

    if (e0 < e1) {
        const int nq4 = (e1 - e0) >> 2;
        const int4* __restrict__ d4p = (const int4*)(dst + e0);
        const int4* __restrict__ s4p = (const int4*)(src + e0);
        const size_t sb = (size_t)bid * SLOTS;

        for (int i = tid; i < nq4; i += 512) {
            int4 d = d4p[i];
            int4 s = s4p[i];
#pragma unroll
            for (int u = 0; u < 4; ++u) {
                int dv = (u == 0) ? d.x : (u == 1) ? d.y : (u == 2) ? d.z : d.w;
                int sv = (u == 0) ? s.x : (u == 1) ? s.y : (u == 2) ? s.z : s.w;
                int rid  = dv >> RSH;
                int slot = atomicAdd(&hist[rid], 1);
                if (slot < SLOTS)
                    seg[(size_t)rid * STR + sb + slot] =
                        (unsigned)(((dv & (RS - 1)) << 16) | (sv & 0xffff));
            }
        }
        for (int e = e0 + (nq4 << 2) + tid; e < e1; e += 512) {
            int dv = dst[e], sv = src[e];
            int rid  = dv >> RSH;
            int slot = atomicAdd(&hist[rid], 1);
            if (slot < SLOTS)
                seg[(size_t)rid * STR + sb + slot] =
                    (unsigned)(((dv & (RS - 1)) << 16) | (sv & 0xffff));
        }
    }
    __syncthreads();

    for (int r = tid; r < NR; r += 512) {
        int c = hist[r]; if (c > SLOTS) c = SLOTS;
        cnt[(size_t)r * PB + bid] = c;
    }

    // ---- hb-pack chunk: quarter-wave (16 lanes) packs one 256-B bf16 row ----
    const int rpb  = (n + PB - 1) / PB;
    const int r0   = bid * rpb;
    int rend = r0 + rpb; if (rend > n) rend = n;
    const int qid = tid >> 4;
    const int ql  = tid & 15;
    const float4* __restrict__ h4 = (const float4*)h;
    for (int r = r0 + qid; r < rend; r += 32) {
        float4 a0 = h4[(size_t)r * 32 + ql * 2];
        float4 a1 = h4[(size_t)r * 32 + ql * 2 + 1];
        hb4[(size_t)r * 16 + ql] = __builtin_bit_cast(uint4, pack8(a0, a1));
    }
}

// ---------------- K2: [bin+gather per range] ++ [gemm -> out] in ONE grid ----------------
// K2 is treated as WALLED at ~48us: three schedules (R0 shuffle, R6 MLP4, R8 pair) all
// land 48-49.5 at VALUBusy ~20% -- ~200 MB mixed random read / 48us ~ 4.1 TB/s is the
// memory-system limit for this pattern. R9 keeps R8's pair-node loop; only the bin scan
// adapts to PB=512/SLOTS=16 (scnt[512], 4 int4-iterations over 8192 slots).
// INVARIANT: shfl_down reduce under FULL exec (pair-loop break wave-uniform); only hb
// load+accumulate predicated. Gemm blocks after gather blocks (R6-verified overlap).
__global__ __launch_bounds__(512) void gather_gemm_kernel(
    const float* __restrict__ h, const float* __restrict__ W,
    const float* __restrict__ b, const uint4* __restrict__ hb4,
    const unsigned* __restrict__ seg, const int* __restrict__ cnt,
    float* __restrict__ out, float* __restrict__ agg, int n, int NR)
{
    __shared__ int            lcnt[RS];
    __shared__ int            scnt[PB];
    __shared__ unsigned short lbkt[RS * CAPN];   // 8 KB; slots >= count stay garbage (never read)

    const int bid = blockIdx.x;
    const int tid = threadIdx.x;

    if (bid < NR) {
        const int base = bid * RS;
        int rsv = n - base; if (rsv > RS) rsv = RS;

        if (tid < RS) lcnt[tid] = 0;
        scnt[tid] = cnt[(size_t)bid * PB + tid];     // PB == 512 == blockDim
        __syncthreads();

        // bin: scan own 8192-slot row, gated by per-stripe counts
        const int4* __restrict__ seg4 = (const int4*)seg + (size_t)bid * (STR / 4);
#pragma unroll
        for (int wv = 0; wv < STR / 4 / 512; ++wv) {    // 4 iterations
            int j4 = wv * 512 + tid;
            int4 pv = seg4[j4];
            int s0 = j4 << 2;
#pragma unroll
            for (int u = 0; u < 4; ++u) {
                int sl = s0 + u;
                unsigned p = (u == 0) ? (unsigned)pv.x : (u == 1) ? (unsigned)pv.y
                           : (u == 2) ? (unsigned)pv.z : (unsigned)pv.w;
                if ((sl & (SLOTS - 1)) < scnt[sl >> SLOTSH]) {
                    int nd = (int)(p >> 16);
                    int k  = atomicAdd(&lcnt[nd], 1);
                    if (k < CAPN) lbkt[(nd << 6) + k] = (unsigned short)(p & 0xffffu);
                }
            }
        }
        __syncthreads();

        const int lane = tid & 63;
        const int w    = tid >> 6;
        const int q    = lane >> 4, ql = lane & 15;
        const int nb   = w << 3;          // this wave's first node

        for (int k = 0; k < 8; k += 2) {
            const int ndA = nb + k, ndB = nb + k + 1;
            if (ndA >= rsv) break;                      // wave-uniform
            const bool hasB = (ndB < rsv);              // wave-uniform
            int degA = lcnt[ndA]; degA = degA > CAPN ? CAPN : degA;
            int degB = hasB ? lcnt[ndB] : 0; degB = degB > CAPN ? CAPN : degB;
            const int dmax = degA > degB ? degA : degB; // wave-uniform (LDS broadcast)
            const int rbA = ndA << 6, rbB = ndB << 6;   // ndB <= 63 always: lbkt read safe

            f32x4 alA0 = {0.f,0.f,0.f,0.f}, ahA0 = {0.f,0.f,0.f,0.f};
            f32x4 alA1 = {0.f,0.f,0.f,0.f}, ahA1 = {0.f,0.f,0.f,0.f};
            f32x4 alB0 = {0.f,0.f,0.f,0.f}, ahB0 = {0.f,0.f,0.f,0.f};
            f32x4 alB1 = {0.f,0.f,0.f,0.f}, ahB1 = {0.f,0.f,0.f,0.f};

            for (int t = 0; t < dmax; t += 16) {
                const int i0 = t + q, i1 = t + 4 + q, i2 = t + 8 + q, i3 = t + 12 + q;
                int eA0 = lbkt[rbA + i0], eA1 = lbkt[rbA + i1];
                int eA2 = lbkt[rbA + i2], eA3 = lbkt[rbA + i3];
                int eB0 = lbkt[rbB + i0], eB1 = lbkt[rbB + i1];
                int eB2 = lbkt[rbB + i2], eB3 = lbkt[rbB + i3];
                uint4 vA0, vA1, vA2, vA3, vB0, vB1, vB2, vB3;
                if (i0 < degA) vA0 = hb4[(size_t)eA0 * 16 + ql];
                if (i1 < degA) vA1 = hb4[(size_t)eA1 * 16 + ql];
                if (i2 < degA) vA2 = hb4[(size_t)eA2 * 16 + ql];
                if (i3 < degA) vA3 = hb4[(size_t)eA3 * 16 + ql];
                if (i0 < degB) vB0 = hb4[(size_t)eB0 * 16 + ql];
                if (i1 < degB) vB1 = hb4[(size_t)eB1 * 16 + ql];
                if (i2 < degB) vB2 = hb4[(size_t)eB2 * 16 + ql];
                if (i3 < degB) vB3 = hb4[(size_t)eB3 * 16 + ql];
                if (i0 < degA) { alA0 += unpack2(vA0.x, vA0.y); ahA0 += unpack2(vA0.z, vA0.w); }
                if (i1 < degA) { alA1 += unpack2(vA1.x, vA1.y); ahA1 += unpack2(vA1.z, vA1.w); }
                if (i2 < degA) { alA0 += unpack2(vA2.x, vA2.y); ahA0 += unpack2(vA2.z, vA2.w); }
                if (i3 < degA) { alA1 += unpack2(vA3.x, vA3.y); ahA1 += unpack2(vA3.z, vA3.w); }
                if (i0 < degB) { alB0 += unpack2(vB0.x, vB0.y); ahB0 += unpack2(vB0.z, vB0.w); }
                if (i1 < degB) { alB1 += unpack2(vB1.x, vB1.y); ahB1 += unpack2(vB1.z, vB1.w); }
                if (i2 < degB) { alB0 += unpack2(vB2.x, vB2.y); ahB0 += unpack2(vB2.z, vB2.w); }
                if (i3 < degB) { alB1 += unpack2(vB3.x, vB3.y); ahB1 += unpack2(vB3.z, vB3.w); }
            }

            alA0 += alA1; ahA0 += ahA1;
            alB0 += alB1; ahB0 += ahB1;

#pragma unroll
            for (int j = 0; j < 4; ++j) {               // FULL exec mask
                alA0[j] += __shfl_down(alA0[j], 32);
                ahA0[j] += __shfl_down(ahA0[j], 32);
                alB0[j] += __shfl_down(alB0[j], 32);
                ahB0[j] += __shfl_down(ahB0[j], 32);
                alA0[j] += __shfl_down(alA0[j], 16);
                ahA0[j] += __shfl_down(ahA0[j], 16);
                alB0[j] += __shfl_down(alB0[j], 16);
                ahB0[j] += __shfl_down(ahB0[j], 16);
            }

            if (q == 0) {
                f32x4* aggv = (f32x4*)agg;
                __builtin_nontemporal_store(alA0, &aggv[(size_t)(base + ndA) * 32 + ql * 2]);
                __builtin_nontemporal_store(ahA0, &aggv[(size_t)(base + ndA) * 32 + ql * 2 + 1]);
                if (hasB) {
                    __builtin_nontemporal_store(alB0, &aggv[(size_t)(base + ndB) * 32 + ql * 2]);
                    __builtin_nontemporal_store(ahB0, &aggv[(size_t)(base + ndB) * 32 + ql * 2 + 1]);
                }
            }
        }
        return;
    }

    // ---- gemm path: wave = rows [r0g, r0g+32) x cols [ch*64, ch*64+64) ----
    const int gbid = bid - NR;
    const int w    = tid >> 6;
    const int lane = tid & 63;
    const int m    = lane & 15, quad = lane >> 4;
    const int r0g  = gbid * 128 + (w >> 1) * 32;
    const int ch   = w & 1;
    if (r0g >= n) return;

    const float4* __restrict__ h4 = (const float4*)h;   // row stride 32 float4
    const float4* __restrict__ W4 = (const float4*)W;

    bf16x8 af[2][4];
#pragma unroll
    for (int mt = 0; mt < 2; ++mt) {
        int gr = r0g + mt * 16 + m;
#pragma unroll
        for (int ks = 0; ks < 4; ++ks) {
            float4 a0 = h4[(size_t)gr * 32 + ks * 8 + quad * 2];
            float4 a1 = h4[(size_t)gr * 32 + ks * 8 + quad * 2 + 1];
            af[mt][ks] = pack8(a0, a1);
        }
    }

    f32x4 acc[2][4];
#pragma unroll
    for (int mt = 0; mt < 2; ++mt)
#pragma unroll
        for (int nn = 0; nn < 4; ++nn) acc[mt][nn] = (f32x4){0.f, 0.f, 0.f, 0.f};

#pragma unroll
    for (int nn = 0; nn < 4; ++nn) {
        int c = (ch * 4 + nn) * 16 + m;
#pragma unroll
        for (int ks = 0; ks < 4; ++ks) {
            float4 b0 = W4[(size_t)c * 32 + ks * 8 + quad * 2];
            float4 b1 = W4[(size_t)c * 32 + ks * 8 + quad * 2 + 1];
            bf16x8 bf = pack8(b0, b1);
#pragma unroll
            for (int mt = 0; mt < 2; ++mt)
                acc[mt][nn] = __builtin_amdgcn_mfma_f32_16x16x32_bf16(
                    af[mt][ks], bf, acc[mt][nn], 0, 0, 0);
        }
    }

#pragma unroll
    for (int nn = 0; nn < 4; ++nn) {
        int col = (ch * 4 + nn) * 16 + m;
        float bias = b[col];
#pragma unroll
        for (int mt = 0; mt < 2; ++mt)
#pragma unroll
            for (int r = 0; r < 4; ++r) {
                int gr = r0g + mt * 16 + quad * 4 + r;
                if (gr < n)
                    __builtin_nontemporal_store(acc[mt][nn][r] + bias,
                                                &out[(size_t)gr * FEAT + col]);
            }
    }
}

// ---------------- fallback path (ws too small / odd shapes): f32 GEMM + atomic scatter ----------------
__global__ __launch_bounds__(256, 2) void gemm_f32_kernel(
    const float* __restrict__ h, const float* __restrict__ W,
    const float* __restrict__ b, float* __restrict__ out, int nrows)
{
    __shared__ float4 wsh[128 * 8];
    __shared__ float4 hsh[64 * 8];
    const int tid = threadIdx.x;
    const int tx  = tid & 31;
    const int ty  = tid >> 5;
    const int r0  = blockIdx.x * 64;
    const float4* __restrict__ W4 = (const float4*)W;
    const float4* __restrict__ h4 = (const float4*)h;
    float acc[8][4];
#pragma unroll
    for (int i = 0; i < 8; ++i)
#pragma unroll
        for (int j = 0; j < 4; ++j) acc[i][j] = 0.f;
    for (int p = 0; p < 4; ++p) {
        if (p) __syncthreads();
#pragma unroll
        for (int l = 0; l < 4; ++l) {
            int flat = l * 256 + tid;
            int c = flat >> 3, kc = flat & 7;
            wsh[c * 8 + (kc ^ ((c >> 2) & 7))] = W4[c * 32 + p * 8 + kc];
        }
#pragma unroll
        for (int l = 0; l < 2; ++l) {
            int flat = l * 256 + tid;
            int r = flat >> 3, kc = flat & 7;
            int gr = r0 + r;
            float4 v = make_float4(0.f, 0.f, 0.f, 0.f);
            if (gr < nrows) v = h4[(size_t)gr * 32 + p * 8 + kc];
            hsh[r * 8 + (kc ^ ((r >> 2) & 7))] = v;
        }
        __syncthreads();
#pragma unroll
        for (int kc = 0; kc < 8; ++kc) {
            float4 wv[4], hv[8];
#pragma unroll
            for (int j = 0; j < 4; ++j) wv[j] = wsh[(4 * tx + j) * 8 + (kc ^ (tx & 7))];
#pragma unroll
            for (int i = 0; i < 8; ++i) {
                int r = 8 * ty + i;
                hv[i] = hsh[r * 8 + (kc ^ ((r >> 2) & 7))];
            }
#pragma unroll
            for (int i = 0; i < 8; ++i)
#pragma unroll
                for (int j = 0; j < 4; ++j) {
                    acc[i][j] += hv[i].x * wv[j].x;
                    acc[i][j] += hv[i].y * wv[j].y;
                    acc[i][j] += hv[i].z * wv[j].z;
                    acc[i][j] += hv[i].w * wv[j].w;
                }
        }
    }
    const float4 bj = ((const float4*)b)[tx];
    float4* out4 = (float4*)out;
#pragma unroll
    for (int i = 0; i < 8; ++i) {
        int gr = r0 + 8 * ty + i;
        if (gr < nrows) {
            float4 o;
            o.x = acc[i][0] + bj.x; o.y = acc[i][1] + bj.y;
            o.z = acc[i][2] + bj.z; o.w = acc[i][3] + bj.w;
            out4[(size_t)gr * 32 + tx] = o;
        }
    }
}

__global__ __launch_bounds__(256) void scatter_add_kernel(
    const float* __restrict__ h, const int* __restrict__ src,
    const int* __restrict__ dst, float* __restrict__ agg, int E)
{
    int gid  = blockIdx.x * 256 + threadIdx.x;
    int e    = gid >> 6;
    int lane = gid & 63;
    if (e >= E) return;
    int s = src[e];
    int d = dst[e];
    const float2* hp = (const float2*)(h + (size_t)s * FEAT);
    float2 v = hp[lane];
    float* ap = agg + (size_t)d * FEAT + 2 * lane;
    unsafeAtomicAdd(ap,     v.x);
    unsafeAtomicAdd(ap + 1, v.y);
}

extern "C" void kernel_launch(void* const* d_in, const int* in_sizes, int n_in,
                              void* d_out, int out_size, void* d_ws, size_t ws_size,
                              hipStream_t stream) {
    const float* h   = (const float*)d_in[0];
    const float* W   = (const float*)d_in[1];
    const float* b   = (const float*)d_in[2];
    const int*   src = (const int*)d_in[3];
    const int*   dst = (const int*)d_in[4];

    const int n = in_sizes[0] / FEAT;   // 40000 nodes
    const int E = in_sizes[3];          // 640000 edges

    float* out = (float*)d_out;
    float* agg = out + (size_t)n * FEAT;

    const int NR = (n + RS - 1) >> RSH;   // ranges of 64 nodes

    // ws layout: [hb: n*256 B][seg: NR*STR*4 B = 20.5 MB][cnt: NR*PB*4 B = 1.25 MB]
    size_t hb_bytes  = (size_t)n * FEAT * 2;
    size_t seg_bytes = (size_t)NR * STR * 4;
    size_t cnt_bytes = (size_t)NR * PB * 4;
    size_t need = hb_bytes + seg_bytes + cnt_bytes;

    bool fast = (ws_size >= need) && (n > 0) && (n <= 65536) && (NR <= NRMAX);

    if (fast) {
        uint4*    hb  = (uint4*)d_ws;
        unsigned* seg = (unsigned*)((char*)d_ws + hb_bytes);
        int*      cnt = (int*)((char*)d_ws + hb_bytes + seg_bytes);

        prep_kernel<<<dim3(PB), dim3(512), 0, stream>>>(
            h, src, dst, hb, seg, cnt, n, E, NR);

        int gemm_blocks = (n + 127) / 128;        // 128 rows/block (8 waves)
        gather_gemm_kernel<<<dim3(NR + gemm_blocks), dim3(512), 0, stream>>>(
            h, W, b, hb, seg, cnt, out, agg, n, NR);
    } else {
        gemm_f32_kernel<<<dim3((n + 63) / 64), dim3(256), 0, stream>>>(h, W, b, out, n);
        (void)hipMemsetAsync(agg, 0, (size_t)n * FEAT * sizeof(float), stream);
        int nblocks = (int)(((long long)E * 64 + 255) / 256);
        scatter_add_kernel<<<dim3(nblocks), dim3(256), 0, stream>>>(h, src, dst, agg, E);
    }
}